// Round 17
// baseline (146.116 us; speedup 1.0000x reference)
//
#include <hip/hip_runtime.h>
#include <hip/hip_bf16.h>
#include <math.h>

#define BATCH  64
#define SEQ    2048
#define DMODEL 512
#define ATT    256
#define M_TOTAL (BATCH * SEQ)

#define MT     256                      // rows per block (m201 geometry)
#define KC     32                       // k per step
#define NSTEP  16
#define PSZ    8192                     // ushorts per 16 KB plane (ATT*KC)
#define WA_LO_OFF (NSTEP * PSZ)         // ushort offset of lo images

#define NBLK   (M_TOTAL / MT)           // 512 fused blocks
#define BPB    (SEQ / MT)               // 8 blocks per batch row

// d_ws layout
#define PF_OFF  (1u << 20)                              // 1 MB: [512][512] f32
#define ML_OFF  (PF_OFF + (size_t)NBLK * DMODEL * 4)    // 4 KB: [512] float2
#define BS_OFF  (ML_OFF + (size_t)NBLK * 8)             // 512 B: [64] float2

typedef __attribute__((ext_vector_type(8))) short short8v;
typedef __attribute__((ext_vector_type(4))) float floatx4;

__device__ __forceinline__ ushort f2bf_rne(float f) {
    unsigned u = __float_as_uint(f);
    u += 0x7FFFu + ((u >> 16) & 1u);
    return (ushort)(u >> 16);
}
__device__ __forceinline__ float bf2f(ushort h) {
    return __uint_as_float(((unsigned)h) << 16);
}
__device__ __forceinline__ void gll16(const void* g, void* l) {
    __builtin_amdgcn_global_load_lds(
        (const __attribute__((address_space(1))) unsigned*)g,
        (__attribute__((address_space(3))) unsigned*)l, 16, 0, 0);
}
// sign-free fast tanh: 1 - 2/(e^{2x}+1); exact at +-inf, 0
__device__ __forceinline__ float fast_tanh(float x) {
    return 1.0f - 2.0f * __builtin_amdgcn_rcpf(__expf(x + x) + 1.0f);
}
// float4 -> packed bf16 hi (truncation) + lo (RNE of remainder)
__device__ __forceinline__ void cvt4(float4 v, uint2& hi, uint2& lo) {
    unsigned u0 = __float_as_uint(v.x), u1 = __float_as_uint(v.y);
    unsigned u2 = __float_as_uint(v.z), u3 = __float_as_uint(v.w);
    hi.x = __builtin_amdgcn_perm(u1, u0, 0x07060302u);   // [bf(y):bf(x)]
    hi.y = __builtin_amdgcn_perm(u3, u2, 0x07060302u);
    float r0 = v.x - __uint_as_float(u0 & 0xFFFF0000u);
    float r1 = v.y - __uint_as_float(u1 & 0xFFFF0000u);
    float r2 = v.z - __uint_as_float(u2 & 0xFFFF0000u);
    float r3 = v.w - __uint_as_float(u3 & 0xFFFF0000u);
    asm("v_cvt_pk_bf16_f32 %0, %1, %2" : "=v"(lo.x) : "v"(r0), "v"(r1));
    asm("v_cvt_pk_bf16_f32 %0, %1, %2" : "=v"(lo.y) : "v"(r2), "v"(r3));
}
__device__ __forceinline__ void cvt8(float4 a, float4 b, uint4& hi, uint4& lo) {
    uint2 h0, l0, h1, l1;
    cvt4(a, h0, l0);
    cvt4(b, h1, l1);
    hi = make_uint4(h0.x, h0.y, h1.x, h1.y);
    lo = make_uint4(l0.x, l0.y, l1.x, l1.y);
}

// K0: Wa fp32 [256][512] -> bf16 hi/lo per-step quad-major images:
// elem (a, k): step kc=k>>5, quad q=(k&31)>>3 -> kc*8192 + (q*256+a)*8 + (k&7)
__global__ __launch_bounds__(256)
void wa_convert_kernel(const float* __restrict__ Wa, ushort* __restrict__ out) {
    int idx = blockIdx.x * 256 + threadIdx.x;   // 131072
    float x = Wa[idx];
    ushort hi = f2bf_rne(x);
    ushort lo = f2bf_rne(x - bf2f(hi));
    int a = idx >> 9, k = idx & 511;
    int kc = k >> 5, kk = k & 31, q = kk >> 3;
    size_t o = (size_t)kc * PSZ + (size_t)(q * 256 + a) * 8 + (kk & 7);
    out[o] = hi;
    out[WA_LO_OFF + o] = lo;
}

// 24 MFMAs for mi pair {2P, 2P+1}: 3 terms x 4 nj x 2 rows
#define MFMA24(P)                                                                        \
    {                                                                                    \
        _Pragma("unroll")                                                                \
        for (int t3 = 0; t3 < 3; ++t3)                                                   \
            _Pragma("unroll")                                                            \
            for (int nj = 0; nj < 4; ++nj)                                               \
                _Pragma("unroll")                                                        \
                for (int m2 = 0; m2 < 2; ++m2) {                                         \
                    short8v aa = (t3 == 0) ? av[m2] : ah[m2];                            \
                    short8v bb2 = (t3 == 1) ? bv[nj] : bh[nj];                           \
                    acc[2 * (P) + m2][nj] =                                              \
                        __builtin_amdgcn_mfma_f32_16x16x32_bf16(aa, bb2, acc[2 * (P) + m2][nj], 0, 0, 0); \
                }                                                                        \
    }

// KF: fused scores GEMM (8-phase-style schedule) + tanh-reduce + block
// softmax + partial GEVM. 512 thr / 8 waves; tile 256x256; wave (wm=wid>>2,
// wn=wid&3): rows [wm*128,+128) x cols [wn*64,+64); acc = 8x4 f32x4 = 128.
// LDS 128 KB: 2 bufs x {A_hi, A_lo, B_hi, B_lo} x 16 KB. 1 block/CU,
// 2 waves/SIMD, 256-reg budget. Per K-step: 4 phases {ds_read; stage-issue;
// s_barrier; setprio+24 MFMA; s_barrier}, syncthreads at step end (= the
// counted gll drain point). Staging: P0 issue A-fp32(t+1); P1 issue B-gll
// (t+1); P2 vmcnt(4)+cvt; P3 ds_write A(t+1).
__global__ __launch_bounds__(512, 2)
void fused_kernel(const float* __restrict__ X,
                  const ushort* __restrict__ wa_cvt,
                  const float* __restrict__ ba,
                  const float* __restrict__ ae,
                  float* __restrict__ zg,
                  float* __restrict__ pfeat,
                  float2* __restrict__ pml) {
    __shared__ __align__(16) ushort pool[2][4][PSZ];   // 128 KiB exactly

    const int tid = threadIdx.x;
    const int l   = tid & 63;
    const int wid = tid >> 6;
    const int wm  = wid >> 2, wn = wid & 3;
    const int n   = l & 15, g = l >> 4;
    const int m0  = blockIdx.x * MT;

    // --- staging addressing (resolved once) ---
    const int r_s = tid >> 1, kh = tid & 1;            // A: row, k-half
    const float* axp = X + (size_t)(m0 + r_s) * DMODEL + kh * 16;
    const int awo0 = ((2 * kh) * 256 + r_s) * 8;       // A write quads
    const int awo1 = ((2 * kh + 1) * 256 + r_s) * 8;
    const int w4 = wid & 3;                            // B gll: 4 waves per plane
    const char* bsrc = (const char*)wa_cvt + (wid < 4 ? 0 : (size_t)WA_LO_OFF * 2)
                       + w4 * 4096 + l * 16;
    const int bplane = (wid < 4) ? 2 : 3;
    // --- fragment offsets (quad-major, ushort units) ---
    int aoff[8], boff[4];
    #pragma unroll
    for (int mi = 0; mi < 8; ++mi) aoff[mi] = (g * 256 + wm * 128 + mi * 16 + n) * 8;
    #pragma unroll
    for (int nj = 0; nj < 4; ++nj) boff[nj] = (g * 256 + wn * 64 + nj * 16 + n) * 8;

    floatx4 acc[8][4];
    #pragma unroll
    for (int i = 0; i < 8; ++i)
        #pragma unroll
        for (int j = 0; j < 4; ++j)
            acc[i][j] = (floatx4){0.f, 0.f, 0.f, 0.f};

    // ---- prologue: stage step 0 into buf 0 ----
    float4 xr[4];
    #pragma unroll
    for (int i = 0; i < 4; ++i) xr[i] = *(const float4*)(axp + i * 4);
    {
        char* dst = (char*)&pool[0][bplane][0] + w4 * 4096;
        #pragma unroll
        for (int i = 0; i < 4; ++i) gll16(bsrc + i * 1024, dst + i * 1024);
    }
    asm volatile("s_waitcnt vmcnt(4)" ::: "memory");   // A fp32 ready; glls fly
    {
        uint4 h0, lo0, h1, lo1;
        cvt8(xr[0], xr[1], h0, lo0);
        cvt8(xr[2], xr[3], h1, lo1);
        *(uint4*)&pool[0][0][awo0] = h0;
        *(uint4*)&pool[0][0][awo1] = h1;
        *(uint4*)&pool[0][1][awo0] = lo0;
        *(uint4*)&pool[0][1][awo1] = lo1;
    }
    __syncthreads();                                   // drains glls + writes

    #pragma unroll 1
    for (int t = 0; t < NSTEP; ++t) {
        const int c = t & 1, nbuf = c ^ 1;
        const bool more = (t + 1 < NSTEP);
        const ushort* Ah = &pool[c][0][0];
        const ushort* Al = &pool[c][1][0];
        const ushort* Bh = &pool[c][2][0];
        const ushort* Bl = &pool[c][3][0];

        short8v bh[4], bv[4], ah[2], av[2];
        uint4 h0, lo0, h1, lo1;

        // ---- phase 0: B frags (held all step) + A mi0/1; issue A-fp32(t+1)
        #pragma unroll
        for (int nj = 0; nj < 4; ++nj) {
            bh[nj] = *(const short8v*)&Bh[boff[nj]];
            bv[nj] = *(const short8v*)&Bl[boff[nj]];
        }
        ah[0] = *(const short8v*)&Ah[aoff[0]]; av[0] = *(const short8v*)&Al[aoff[0]];
        ah[1] = *(const short8v*)&Ah[aoff[1]]; av[1] = *(const short8v*)&Al[aoff[1]];
        if (more) {
            #pragma unroll
            for (int i = 0; i < 4; ++i)
                xr[i] = *(const float4*)(axp + (t + 1) * KC + i * 4);
        }
        __builtin_amdgcn_s_barrier();
        __builtin_amdgcn_s_setprio(1);
        MFMA24(0);
        __builtin_amdgcn_s_setprio(0);
        __builtin_amdgcn_s_barrier();

        // ---- phase 1: A mi2/3; issue B glls(t+1)
        ah[0] = *(const short8v*)&Ah[aoff[2]]; av[0] = *(const short8v*)&Al[aoff[2]];
        ah[1] = *(const short8v*)&Ah[aoff[3]]; av[1] = *(const short8v*)&Al[aoff[3]];
        if (more) {
            const char* src = bsrc + (t + 1) * 16384;
            char* dst = (char*)&pool[nbuf][bplane][0] + w4 * 4096;
            #pragma unroll
            for (int i = 0; i < 4; ++i) gll16(src + i * 1024, dst + i * 1024);
        }
        __builtin_amdgcn_s_barrier();
        __builtin_amdgcn_s_setprio(1);
        MFMA24(1);
        __builtin_amdgcn_s_setprio(0);
        __builtin_amdgcn_s_barrier();

        // ---- phase 2: A mi4/5; wait A-fp32 (leave glls flying); cvt
        ah[0] = *(const short8v*)&Ah[aoff[4]]; av[0] = *(const short8v*)&Al[aoff[4]];
        ah[1] = *(const short8v*)&Ah[aoff[5]]; av[1] = *(const short8v*)&Al[aoff[5]];
        if (more) {
            asm volatile("s_waitcnt vmcnt(4)" ::: "memory");
            cvt8(xr[0], xr[1], h0, lo0);
            cvt8(xr[2], xr[3], h1, lo1);
        }
        __builtin_amdgcn_s_barrier();
        __builtin_amdgcn_s_setprio(1);
        MFMA24(2);
        __builtin_amdgcn_s_setprio(0);
        __builtin_amdgcn_s_barrier();

        // ---- phase 3: A mi6/7; ds_write A(t+1); step-end syncthreads
        ah[0] = *(const short8v*)&Ah[aoff[6]]; av[0] = *(const short8v*)&Al[aoff[6]];
        ah[1] = *(const short8v*)&Ah[aoff[7]]; av[1] = *(const short8v*)&Al[aoff[7]];
        if (more) {
            *(uint4*)&pool[nbuf][0][awo0] = h0;
            *(uint4*)&pool[nbuf][0][awo1] = h1;
            *(uint4*)&pool[nbuf][1][awo0] = lo0;
            *(uint4*)&pool[nbuf][1][awo1] = lo1;
        }
        __builtin_amdgcn_s_barrier();
        __builtin_amdgcn_s_setprio(1);
        MFMA24(3);
        __builtin_amdgcn_s_setprio(0);
        __syncthreads();             // drains glls(t+1) + A writes; next buf ready
    }

    // ---- epilogue: pool reused. zb[4][256] | pbuf[256] | red[8]
    float* zb   = (float*)&pool[0][0][0];
    float* pbuf = zb + 1024;
    float* red  = pbuf + 256;

    float bav[4], aev[4];
    #pragma unroll
    for (int nj = 0; nj < 4; ++nj) {
        int col = wn * 64 + nj * 16 + n;
        bav[nj] = ba[col];
        aev[nj] = ae[col];
    }
    // C/D map (HW-verified): row = wm*128 + mi*16 + g*4 + e, col = wn*64 + nj*16 + n
    #pragma unroll
    for (int mi = 0; mi < 8; ++mi) {
        float zp[4] = {0.f, 0.f, 0.f, 0.f};
        #pragma unroll
        for (int nj = 0; nj < 4; ++nj)
            #pragma unroll
            for (int e = 0; e < 4; ++e)
                zp[e] += fast_tanh(acc[mi][nj][e] + bav[nj]) * aev[nj];
        #pragma unroll
        for (int off = 8; off >= 1; off >>= 1)
            #pragma unroll
            for (int e = 0; e < 4; ++e)
                zp[e] += __shfl_xor(zp[e], off, 64);
        if (n == 0)
            *(float4*)&zb[wn * 256 + wm * 128 + mi * 16 + g * 4] =
                make_float4(zp[0], zp[1], zp[2], zp[3]);
    }
    __syncthreads();

    // block softmax partials over 256 rows (4 waves)
    float zsum = 0.f;
    if (tid < MT) {
        zsum = (zb[tid] + zb[256 + tid]) + (zb[512 + tid] + zb[768 + tid]);
        zg[m0 + tid] = zsum;
        float mloc = zsum;
        #pragma unroll
        for (int off = 32; off >= 1; off >>= 1)
            mloc = fmaxf(mloc, __shfl_xor(mloc, off, 64));
        if (l == 0) red[wid] = mloc;
    }
    __syncthreads();
    if (tid < MT) {
        float M = fmaxf(fmaxf(red[0], red[1]), fmaxf(red[2], red[3]));
        float p = __expf(zsum - M);
        pbuf[tid] = p;
        float s = p;
        #pragma unroll
        for (int off = 32; off >= 1; off >>= 1)
            s += __shfl_xor(s, off, 64);
        if (l == 0) red[4 + wid] = s;
    }
    __syncthreads();
    if (tid == 0)
        pml[blockIdx.x] = make_float2(
            fmaxf(fmaxf(red[0], red[1]), fmaxf(red[2], red[3])),
            (red[4] + red[5]) + (red[6] + red[7]));

    // partial feature GEVM: pfeat[blk][f] = sum_s p[s]*X[m0+s][f] (L2-hot)
    {
        float a0 = 0.f, a1 = 0.f, a2 = 0.f, a3 = 0.f;
        const float* xc = X + (size_t)m0 * DMODEL + tid;
        #pragma unroll 4
        for (int s = 0; s < MT; s += 4) {
            a0 = fmaf(xc[(size_t)(s + 0) * DMODEL], pbuf[s + 0], a0);
            a1 = fmaf(xc[(size_t)(s + 1) * DMODEL], pbuf[s + 1], a1);
            a2 = fmaf(xc[(size_t)(s + 2) * DMODEL], pbuf[s + 2], a2);
            a3 = fmaf(xc[(size_t)(s + 3) * DMODEL], pbuf[s + 3], a3);
        }
        pfeat[(size_t)blockIdx.x * DMODEL + tid] = (a0 + a1) + (a2 + a3);
    }
}

// K-combine: per batch, merge 8 block partials with online-softmax rescale.
__global__ __launch_bounds__(512)
void combine_kernel(const float* __restrict__ pfeat, const float2* __restrict__ pml,
                    float* __restrict__ feat, float2* __restrict__ bstat) {
    const int b = blockIdx.x, tid = threadIdx.x;
    float M = -3.0e38f;
    #pragma unroll
    for (int c = 0; c < BPB; ++c)
        M = fmaxf(M, pml[b * BPB + c].x);
    float L = 0.f, s = 0.f;
    #pragma unroll
    for (int c = 0; c < BPB; ++c) {
        float2 ml = pml[b * BPB + c];
        float sc = __expf(ml.x - M);
        L += sc * ml.y;
        s = fmaf(sc, pfeat[(size_t)(b * BPB + c) * DMODEL + tid], s);
    }
    feat[(size_t)b * DMODEL + tid] = s / L;
    if (tid == 0) bstat[b] = make_float2(M, L);
}

// K-weights: w[b,s] = exp(z - M_b) / L_b, in place over zg.
__global__ __launch_bounds__(256)
void weights_kernel(float* __restrict__ zw, const float2* __restrict__ bstat) {
    int i = blockIdx.x * 256 + threadIdx.x;   // 131072
    float2 ml = bstat[i >> 11];               // SEQ = 2048
    zw[i] = __expf(zw[i] - ml.x) / ml.y;
}

extern "C" void kernel_launch(void* const* d_in, const int* in_sizes, int n_in,
                              void* d_out, int out_size, void* d_ws, size_t ws_size,
                              hipStream_t stream) {
    const float* X  = (const float*)d_in[0];
    const float* Wa = (const float*)d_in[1];
    const float* ba = (const float*)d_in[2];
    const float* ae = (const float*)d_in[3];
    float* out  = (float*)d_out;
    float* feat = out;                       // [64][512]
    float* wgt  = out + BATCH * DMODEL;      // [64][2048]; holds z then weights

    ushort* wa_cvt  = (ushort*)d_ws;                          // 512 KB
    float*  pfeat   = (float*)((char*)d_ws + PF_OFF);         // 1 MB
    float2* pml     = (float2*)((char*)d_ws + ML_OFF);        // 4 KB
    float2* bstat   = (float2*)((char*)d_ws + BS_OFF);        // 512 B

    wa_convert_kernel<<<ATT * DMODEL / 256, 256, 0, stream>>>(Wa, wa_cvt);
    fused_kernel<<<NBLK, 512, 0, stream>>>(X, wa_cvt, ba, ae, wgt, pfeat, pml);
    combine_kernel<<<BATCH, 512, 0, stream>>>(pfeat, pml, feat, bstat);
    weights_kernel<<<M_TOTAL / 256, 256, 0, stream>>>(wgt, bstat);
}